// Round 5
// baseline (130.309 us; speedup 1.0000x reference)
//
#include <hip/hip_runtime.h>

#define N_IMG 256
#define H_IMG 512
#define W_IMG 512

typedef float f32x4 __attribute__((ext_vector_type(4)));

// mirror for idx in [-P, P]: jnp mod semantics then reflect.
__device__ __forceinline__ int mirror_small(int idx, int n, int P) {
    int m = idx;
    if (m < 0) m += P;
    return (m >= n) ? (P - m) : m;
}

__global__ __launch_bounds__(128) void FluxPosRegressor_shift_kernel(
    const float* __restrict__ imgs,
    const float* __restrict__ flux,
    const float* __restrict__ noise,
    const float* __restrict__ dxdy,
    float* __restrict__ out)
{
    const int n   = blockIdx.z;
    const int row = blockIdx.y;
    const int tid = threadIdx.x;

    const float dx = dxdy[2 * n + 0];
    const float dy = dxdy[2 * n + 1];
    const float fl = flux[n];
    const float no = noise[n];

    // row interpolation (exactly as reference)
    const float rf  = (float)row + dy;
    const float r0f = floorf(rf);
    const float tr  = rf - r0f;
    const int   r0  = (int)r0f;
    const int   PH  = 2 * (H_IMG - 1);
    const int   mr0 = mirror_small(r0,     H_IMG, PH);
    const int   mr1 = mirror_small(r0 + 1, H_IMG, PH);

    const float* __restrict__ row0 = imgs + ((size_t)n * H_IMG + mr0) * W_IMG;
    const float* __restrict__ row1 = imgs + ((size_t)n * H_IMG + mr1) * W_IMG;
    float* __restrict__ orow       = out  + ((size_t)n * H_IMG + row) * W_IMG;

    // uniform column shift: floor(col + dx) == col + floor(dx) for integer col
    const int   s   = (int)floorf(dx);
    const float tc  = dx - (float)s;           // uniform fractional weight
    const int   rot = s & 3;                   // works for negative s (two's complement)
    const int   b   = 4 * tid + (s - rot);     // 16B-aligned base index (may be OOB at edges)
    const int   bl  = min(max(b, 0), W_IMG - 8); // clamped safe base (still multiple of 4)

    const f32x4* r0v = reinterpret_cast<const f32x4*>(row0);
    const f32x4* r1v = reinterpret_cast<const f32x4*>(row1);
    const f32x4 A0 = r0v[bl >> 2], B0 = r0v[(bl >> 2) + 1];
    const f32x4 A1 = r1v[bl >> 2], B1 = r1v[(bl >> 2) + 1];

    // select elems (rot .. rot+4) of the 8 loaded floats; rot is wave-uniform
    float v0[5], v1[5];
    const int rot_s = __builtin_amdgcn_readfirstlane(rot);
    switch (rot_s) {
      default:
      case 0: v0[0]=A0.x; v0[1]=A0.y; v0[2]=A0.z; v0[3]=A0.w; v0[4]=B0.x;
              v1[0]=A1.x; v1[1]=A1.y; v1[2]=A1.z; v1[3]=A1.w; v1[4]=B1.x; break;
      case 1: v0[0]=A0.y; v0[1]=A0.z; v0[2]=A0.w; v0[3]=B0.x; v0[4]=B0.y;
              v1[0]=A1.y; v1[1]=A1.z; v1[2]=A1.w; v1[3]=B1.x; v1[4]=B1.y; break;
      case 2: v0[0]=A0.z; v0[1]=A0.w; v0[2]=B0.x; v0[3]=B0.y; v0[4]=B0.z;
              v1[0]=A1.z; v1[1]=A1.w; v1[2]=B1.x; v1[3]=B1.y; v1[4]=B1.z; break;
      case 3: v0[0]=A0.w; v0[1]=B0.x; v0[2]=B0.y; v0[3]=B0.z; v0[4]=B0.w;
              v1[0]=A1.w; v1[1]=B1.x; v1[2]=B1.y; v1[3]=B1.z; v1[4]=B1.w; break;
    }

    float res[4];
#pragma unroll
    for (int j = 0; j < 4; ++j) {
        const float top = (1.0f - tc) * v0[j] + tc * v0[j + 1];
        const float bot = (1.0f - tc) * v1[j] + tc * v1[j + 1];
        const float v   = (1.0f - tr) * top + tr * bot;
        res[j] = fmaf(v, fl, no);
    }

    if (b != bl) {  // edge lanes only (<=2 per wave): mirrored scalar gathers
        const int PW = 2 * (W_IMG - 1);
#pragma unroll
        for (int j = 0; j < 4; ++j) {
            const int c0  = 4 * tid + j + s;
            const int mc0 = mirror_small(c0,     W_IMG, PW);
            const int mc1 = mirror_small(c0 + 1, W_IMG, PW);
            const float top = (1.0f - tc) * row0[mc0] + tc * row0[mc1];
            const float bot = (1.0f - tc) * row1[mc0] + tc * row1[mc1];
            res[j] = fmaf((1.0f - tr) * top + tr * bot, fl, no);
        }
    }

    f32x4 r4;
    r4.x = res[0]; r4.y = res[1]; r4.z = res[2]; r4.w = res[3];
    __builtin_nontemporal_store(r4, reinterpret_cast<f32x4*>(orow) + tid);
}

extern "C" void kernel_launch(void* const* d_in, const int* in_sizes, int n_in,
                              void* d_out, int out_size, void* d_ws, size_t ws_size,
                              hipStream_t stream) {
    const float* imgs  = (const float*)d_in[0];
    const float* flux  = (const float*)d_in[1];
    const float* noise = (const float*)d_in[2];
    const float* dxdy  = (const float*)d_in[3];
    float* out = (float*)d_out;

    dim3 block(128, 1, 1);
    dim3 grid(1, H_IMG, N_IMG);   // one block per output row
    FluxPosRegressor_shift_kernel<<<grid, block, 0, stream>>>(imgs, flux, noise, dxdy, out);
}

// Round 6
// 79.650 us; speedup vs baseline: 1.6360x; 1.6360x over previous
//
#include <hip/hip_runtime.h>

#define N_IMG 256
#define H_IMG 512
#define W_IMG 512

// mirror for idx in [-P, P]: jnp mod semantics then reflect.
__device__ __forceinline__ int mirror_small(int idx, int n, int P) {
    int m = idx;
    if (m < 0) m += P;
    return (m >= n) ? (P - m) : m;
}

__global__ __launch_bounds__(128) void FluxPosRegressor_shift_kernel(
    const float* __restrict__ imgs,
    const float* __restrict__ flux,
    const float* __restrict__ noise,
    const float* __restrict__ dxdy,
    float* __restrict__ out)
{
    const int n = blockIdx.z;
    // XCD-chunked row swizzle: consecutive launch-order blocks (y fastest,
    // XCD = y%8 round-robin) get CONTIGUOUS row bands per XCD, so the two
    // output rows sharing an input row live in the same XCD L2.
    const int y   = blockIdx.y;
    const int row = (y & 7) * (H_IMG / 8) + (y >> 3);
    const int tid = threadIdx.x;

    const float dx = dxdy[2 * n + 0];
    const float dy = dxdy[2 * n + 1];
    const float fl = flux[n];
    const float no = noise[n];

    // row interpolation coords (match reference f32 arithmetic exactly)
    const float rf  = (float)row + dy;
    const float r0f = floorf(rf);
    const float tr  = rf - r0f;
    const int   r0  = (int)r0f;
    const int   PH  = 2 * (H_IMG - 1);
    const int   mr0 = mirror_small(r0,     H_IMG, PH);
    const int   mr1 = mirror_small(r0 + 1, H_IMG, PH);

    const float* __restrict__ row0 = imgs + ((size_t)n * H_IMG + mr0) * W_IMG;
    const float* __restrict__ row1 = imgs + ((size_t)n * H_IMG + mr1) * W_IMG;
    float* __restrict__ orow       = out  + ((size_t)n * H_IMG + row) * W_IMG;

    const int PW = 2 * (W_IMG - 1);  // 1022

#pragma unroll
    for (int k = 0; k < 4; ++k) {
        const int   col = tid + k * 128;       // strided: lane-stride 4B -> coalesced
        const float cf  = (float)col + dx;
        const float c0f = floorf(cf);
        const float tc  = cf - c0f;
        const int   c0  = (int)c0f;

        // |dx| << PW, so c0 in (-PW, PW): comparison-based mirror, no division
        int m = c0;
        if (m < 0) m += PW;
        const int mc0 = (m >= W_IMG) ? (PW - m) : m;
        int m1 = m + 1;                        // m in [0,PW) -> m1 in [1,PW]
        const int mc1 = (m1 >= W_IMG) ? (PW - m1) : m1;

        const float g00 = row0[mc0];
        const float g01 = row0[mc1];
        const float g10 = row1[mc0];
        const float g11 = row1[mc1];

        const float top = (1.0f - tc) * g00 + tc * g01;
        const float bot = (1.0f - tc) * g10 + tc * g11;
        const float v   = (1.0f - tr) * top + tr * bot;
        __builtin_nontemporal_store(fmaf(v, fl, no), &orow[col]);
    }
}

extern "C" void kernel_launch(void* const* d_in, const int* in_sizes, int n_in,
                              void* d_out, int out_size, void* d_ws, size_t ws_size,
                              hipStream_t stream) {
    const float* imgs  = (const float*)d_in[0];
    const float* flux  = (const float*)d_in[1];
    const float* noise = (const float*)d_in[2];
    const float* dxdy  = (const float*)d_in[3];
    float* out = (float*)d_out;

    dim3 block(128, 1, 1);
    dim3 grid(1, H_IMG, N_IMG);   // one block per output row (row swizzled in-kernel)
    FluxPosRegressor_shift_kernel<<<grid, block, 0, stream>>>(imgs, flux, noise, dxdy, out);
}